// Round 3
// baseline (127.169 us; speedup 1.0000x reference)
//
#include <hip/hip_runtime.h>
#include <hip/hip_bf16.h>
#include <stdint.h>

typedef __attribute__((ext_vector_type(8))) short short8;
typedef __attribute__((ext_vector_type(4))) float f32x4;

#define N_HEADS 12
#define HD      64
#define BSZ     8
#define TSZ     1024
#define CSZ     768
#define MSZ     (BSZ * TSZ)   /* 8192 */
#define N3      (3 * CSZ)     /* 2304 */
#define LDA     72            /* padded LDS stride (elems); 72*2=144 B keeps 16B align */

static __device__ __forceinline__ unsigned short f2bf(float f) {
    union { float f; uint32_t u; } v; v.f = f;
    uint32_t r = v.u + 0x7fffu + ((v.u >> 16) & 1u);
    return (unsigned short)(r >> 16);
}

// ---------------- fp32 -> bf16 conversion ----------------
__global__ void cvt_f32_to_bf16(const float* __restrict__ s,
                                unsigned short* __restrict__ d, int n) {
    int i = (blockIdx.x * blockDim.x + threadIdx.x) * 4;
    if (i + 3 < n) {
        float4 f = *reinterpret_cast<const float4*>(s + i);
        ushort4 u;
        u.x = f2bf(f.x); u.y = f2bf(f.y); u.z = f2bf(f.z); u.w = f2bf(f.w);
        *reinterpret_cast<ushort4*>(d + i) = u;
    }
}

// ---------------- QKV projection GEMM ----------------
// C[m][n] = sum_k x[m][k] * W[n][k] + b[n];  m=b*1024+t, n in [0,2304)
// Epilogue: q scaled by 0.125 -> qo[(b*12+h)][t][d]; k -> ko same layout;
// v -> vto[(b*12+h)][d][t] (transposed for PV B-fragments).
__global__ __launch_bounds__(256, 2) void qkv_gemm(
    const unsigned short* __restrict__ xb,   // [8192][768] bf16
    const unsigned short* __restrict__ wb,   // [2304][768] bf16
    const float* __restrict__ bias,          // [2304] f32
    unsigned short* __restrict__ qo,
    unsigned short* __restrict__ ko,
    unsigned short* __restrict__ vto)
{
    __shared__ unsigned short At[128 * LDA];
    __shared__ unsigned short Bt[128 * LDA];
    const int tid = threadIdx.x;
    const int lane = tid & 63;
    const int w = tid >> 6;
    const int lr = lane >> 4, lc = lane & 15;
    const int m0 = blockIdx.y * 128;
    const int n0 = blockIdx.x * 128;
    const int wm = (w >> 1) * 64, wn = (w & 1) * 64;

    f32x4 acc[4][4] = {};

    for (int kt = 0; kt < CSZ; kt += 64) {
        __syncthreads();
        #pragma unroll
        for (int i = 0; i < 4; ++i) {
            int e = (i * 256 + tid) * 8;
            int row = e >> 6, kk = e & 63;
            *reinterpret_cast<short8*>(At + row * LDA + kk) =
                *reinterpret_cast<const short8*>(xb + (size_t)(m0 + row) * CSZ + kt + kk);
            *reinterpret_cast<short8*>(Bt + row * LDA + kk) =
                *reinterpret_cast<const short8*>(wb + (size_t)(n0 + row) * CSZ + kt + kk);
        }
        __syncthreads();
        #pragma unroll
        for (int ks = 0; ks < 2; ++ks) {
            short8 af[4], bf[4];
            #pragma unroll
            for (int mi = 0; mi < 4; ++mi)
                af[mi] = *reinterpret_cast<const short8*>(
                    At + (wm + mi * 16 + lc) * LDA + ks * 32 + lr * 8);
            #pragma unroll
            for (int ni = 0; ni < 4; ++ni)
                bf[ni] = *reinterpret_cast<const short8*>(
                    Bt + (wn + ni * 16 + lc) * LDA + ks * 32 + lr * 8);
            #pragma unroll
            for (int mi = 0; mi < 4; ++mi)
                #pragma unroll
                for (int ni = 0; ni < 4; ++ni)
                    acc[mi][ni] = __builtin_amdgcn_mfma_f32_16x16x32_bf16(
                        af[mi], bf[ni], acc[mi][ni], 0, 0, 0);
        }
    }

    // 768 is a multiple of 128, so the q/k/v section is uniform per block.
    const int sec = n0 / CSZ;
    const int nb = n0 - sec * CSZ;
    #pragma unroll
    for (int ni = 0; ni < 4; ++ni) {
        int ncol = wn + ni * 16 + lc;       // 0..127 within block
        int nn = nb + ncol;                 // 0..767 within section
        float badd = bias[n0 + ncol];
        int h = nn >> 6, d = nn & 63;
        #pragma unroll
        for (int mi = 0; mi < 4; ++mi) {
            #pragma unroll
            for (int r = 0; r < 4; ++r) {
                int m = m0 + wm + mi * 16 + lr * 4 + r;
                int bb = m >> 10, t = m & 1023;
                int plane = bb * N_HEADS + h;
                float v = acc[mi][ni][r] + badd;
                if (sec == 0)
                    qo[((size_t)plane * TSZ + t) * HD + d] = f2bf(v * 0.125f);
                else if (sec == 1)
                    ko[((size_t)plane * TSZ + t) * HD + d] = f2bf(v);
                else
                    vto[((size_t)plane * HD + d) * TSZ + t] = f2bf(v);
            }
        }
    }
}

// ---------------- causal-ReLU attention ----------------
// One wave (64 threads) per 64 query rows of one (b,h).
// S^T = mfma(K_frag as A, Q_frag as B)  ->  C-layout packs 4 consecutive kv
// per lane -> mask+ReLU -> packed bf16 ds_write_b64 into S[q][kv] layout.
// PV: y += mfma(S_frag from LDS, V^T_frag from global).
__global__ __launch_bounds__(64, 2) void attn_kernel(
    const unsigned short* __restrict__ q,    // [96][1024][64] bf16 (pre-scaled)
    const unsigned short* __restrict__ k,    // [96][1024][64] bf16
    const unsigned short* __restrict__ vt,   // [96][64][1024] bf16
    float* __restrict__ out)                 // [8][1024][768] f32
{
    __shared__ unsigned short smem[64 * LDA];
    const int lane = threadIdx.x & 63;
    const int lr = lane >> 4, lc = lane & 15;
    const int qw = blockIdx.x;               // 0..15: which 64-row q tile
    const int bh = blockIdx.y;               // 0..95
    const int b = bh / N_HEADS, h = bh - b * N_HEADS;
    const size_t base = (size_t)bh * (TSZ * HD);
    const int qrow0 = qw * 64;

    // Q fragments (reused as MFMA B operand for the S^T trick)
    short8 aq[2][4];
    #pragma unroll
    for (int ks = 0; ks < 2; ++ks)
        #pragma unroll
        for (int qi = 0; qi < 4; ++qi)
            aq[ks][qi] = *reinterpret_cast<const short8*>(
                q + base + (size_t)(qrow0 + qi * 16 + lc) * HD + ks * 32 + lr * 8);

    f32x4 y[4][4] = {};

    for (int kt = 0; kt <= qw; ++kt) {
        const int kv0 = kt * 64;
        f32x4 st[4][4] = {};   // S^T fragments: rows kv, cols q
        #pragma unroll
        for (int ks = 0; ks < 2; ++ks) {
            short8 ak[4];
            #pragma unroll
            for (int ki = 0; ki < 4; ++ki)
                ak[ki] = *reinterpret_cast<const short8*>(
                    k + base + (size_t)(kv0 + ki * 16 + lc) * HD + ks * 32 + lr * 8);
            #pragma unroll
            for (int ki = 0; ki < 4; ++ki)
                #pragma unroll
                for (int qi = 0; qi < 4; ++qi)
                    st[ki][qi] = __builtin_amdgcn_mfma_f32_16x16x32_bf16(
                        ak[ki], aq[ks][qi], st[ki][qi], 0, 0, 0);
        }
        const bool diag = (kt == qw);
        #pragma unroll
        for (int ki = 0; ki < 4; ++ki) {
            #pragma unroll
            for (int qi = 0; qi < 4; ++qi) {
                float vv[4];
                #pragma unroll
                for (int r = 0; r < 4; ++r) {
                    float s = st[ki][qi][r];
                    s = s > 0.0f ? s : 0.0f;                       // ReLU
                    if (diag && (ki * 16 + lr * 4 + r > qi * 16 + lc))
                        s = 0.0f;                                   // causal mask
                    vv[r] = s;
                }
                uint2 pk;
                pk.x = (unsigned)f2bf(vv[0]) | ((unsigned)f2bf(vv[1]) << 16);
                pk.y = (unsigned)f2bf(vv[2]) | ((unsigned)f2bf(vv[3]) << 16);
                // S[q][kv] layout: 4 consecutive kv per lane -> one b64 write
                *reinterpret_cast<uint2*>(
                    smem + (qi * 16 + lc) * LDA + ki * 16 + lr * 4) = pk;
            }
        }
        // PV: y[q][d] += S[q][kv] * V[kv][d]  (V via transposed vt[d][kv])
        #pragma unroll
        for (int ks = 0; ks < 2; ++ks) {
            short8 as[4], bv[4];
            #pragma unroll
            for (int qi = 0; qi < 4; ++qi)
                as[qi] = *reinterpret_cast<const short8*>(
                    smem + (qi * 16 + lc) * LDA + ks * 32 + lr * 8);
            #pragma unroll
            for (int di = 0; di < 4; ++di)
                bv[di] = *reinterpret_cast<const short8*>(
                    vt + (size_t)bh * (HD * TSZ) + (size_t)(di * 16 + lc) * TSZ
                       + kv0 + ks * 32 + lr * 8);
            #pragma unroll
            for (int qi = 0; qi < 4; ++qi)
                #pragma unroll
                for (int di = 0; di < 4; ++di)
                    y[qi][di] = __builtin_amdgcn_mfma_f32_16x16x32_bf16(
                        as[qi], bv[di], y[qi][di], 0, 0, 0);
        }
    }

    #pragma unroll
    for (int qi = 0; qi < 4; ++qi)
        #pragma unroll
        for (int di = 0; di < 4; ++di)
            #pragma unroll
            for (int r = 0; r < 4; ++r) {
                int t = qrow0 + qi * 16 + lr * 4 + r;
                int d = di * 16 + lc;
                out[((size_t)b * TSZ + t) * CSZ + h * HD + d] = y[qi][di][r];
            }
}

extern "C" void kernel_launch(void* const* d_in, const int* in_sizes, int n_in,
                              void* d_out, int out_size, void* d_ws, size_t ws_size,
                              hipStream_t stream) {
    const float* x    = (const float*)d_in[0];
    const float* W    = (const float*)d_in[1];
    const float* bias = (const float*)d_in[2];
    float* out = (float*)d_out;

    unsigned short* xb  = (unsigned short*)d_ws;                 // 8192*768
    unsigned short* wb  = xb + (size_t)MSZ * CSZ;                // 2304*768
    unsigned short* qo  = wb + (size_t)N3 * CSZ;                 // 96*1024*64
    unsigned short* ko  = qo + (size_t)MSZ * CSZ;
    unsigned short* vto = ko + (size_t)MSZ * CSZ;

    const int nx = MSZ * CSZ;   // 6291456
    const int nw = N3 * CSZ;    // 1769472
    cvt_f32_to_bf16<<<nx / 1024, 256, 0, stream>>>(x, xb, nx);
    cvt_f32_to_bf16<<<nw / 1024, 256, 0, stream>>>(W, wb, nw);
    qkv_gemm<<<dim3(N3 / 128, MSZ / 128), 256, 0, stream>>>(xb, wb, bias, qo, ko, vto);
    attn_kernel<<<dim3(TSZ / 64, BSZ * N_HEADS), 256 / 4, 0, stream>>>(qo, ko, vto, out);
}

// Round 5
// 118.331 us; speedup vs baseline: 1.0747x; 1.0747x over previous
//
#include <hip/hip_runtime.h>
#include <hip/hip_bf16.h>
#include <stdint.h>

typedef __attribute__((ext_vector_type(8))) short short8;
typedef __attribute__((ext_vector_type(4))) float f32x4;

#define N_HEADS 12
#define HD      64
#define BSZ     8
#define TSZ     1024
#define CSZ     768
#define MSZ     (BSZ * TSZ)   /* 8192 */
#define N3      (3 * CSZ)     /* 2304 */
#define LDA     72            /* padded LDS stride for attn S-tile */

static __device__ __forceinline__ unsigned short f2bf(float f) {
    union { float f; uint32_t u; } v; v.f = f;
    uint32_t r = v.u + 0x7fffu + ((v.u >> 16) & 1u);
    return (unsigned short)(r >> 16);
}

// async global->LDS, 16B per lane, LDS dest = wave-uniform base + lane*16
static __device__ __forceinline__ void gload16(const unsigned short* g,
                                               unsigned short* l) {
    __builtin_amdgcn_global_load_lds(
        (const __attribute__((address_space(1))) void*)g,
        (__attribute__((address_space(3))) void*)l, 16, 0, 0);
}

// ---------------- fp32 -> bf16 conversion ----------------
__global__ void cvt_f32_to_bf16(const float* __restrict__ s,
                                unsigned short* __restrict__ d, int n) {
    int i = (blockIdx.x * blockDim.x + threadIdx.x) * 4;
    if (i + 3 < n) {
        float4 f = *reinterpret_cast<const float4*>(s + i);
        ushort4 u;
        u.x = f2bf(f.x); u.y = f2bf(f.y); u.z = f2bf(f.z); u.w = f2bf(f.w);
        *reinterpret_cast<ushort4*>(d + i) = u;
    }
}

// ---------------- QKV projection GEMM (m97 structure) ----------------
// C[m][n] = sum_k x[m][k] * W[n][k] + b[n]; global_load_lds width-16 staging
// into linear LDS [128][64]; 2 barriers per K-step; 4 waves, 64x64 per wave.
__global__ __launch_bounds__(256, 2) void qkv_gemm(
    const unsigned short* __restrict__ xb,   // [8192][768] bf16
    const unsigned short* __restrict__ wb,   // [2304][768] bf16
    const float* __restrict__ bias,          // [2304] f32
    unsigned short* __restrict__ qo,
    unsigned short* __restrict__ ko,
    unsigned short* __restrict__ vto)
{
    __shared__ unsigned short At[128 * 64];
    __shared__ unsigned short Bt[128 * 64];
    const int tid = threadIdx.x;
    const int lane = tid & 63;
    const int w = tid >> 6;
    const int lr = lane >> 4, lc = lane & 15;
    const int m0 = blockIdx.y * 128;
    const int n0 = blockIdx.x * 128;
    const int wm = (w >> 1) * 64, wn = (w & 1) * 64;

    // staging geometry: wave w stages rows [w*32, w*32+32) of each tile;
    // op j covers 8 rows; lane l -> row j*8 + (l>>3), col (l&7)*8
    const unsigned short* ga = xb + (size_t)(m0 + w * 32 + (lane >> 3)) * CSZ + (lane & 7) * 8;
    const unsigned short* gb = wb + (size_t)(n0 + w * 32 + (lane >> 3)) * CSZ + (lane & 7) * 8;
    unsigned short* la = At + (w * 32) * 64;
    unsigned short* lb = Bt + (w * 32) * 64;

    f32x4 acc[4][4] = {};

    for (int kt = 0; kt < CSZ; kt += 64) {
        __syncthreads();
        #pragma unroll
        for (int j = 0; j < 4; ++j) {
            gload16(ga + (size_t)j * 8 * CSZ + kt, la + j * 8 * 64);
            gload16(gb + (size_t)j * 8 * CSZ + kt, lb + j * 8 * 64);
        }
        __syncthreads();   // compiler drains vmcnt(0) before s_barrier
        #pragma unroll
        for (int ks = 0; ks < 2; ++ks) {
            short8 af[4], bf[4];
            #pragma unroll
            for (int mi = 0; mi < 4; ++mi)
                af[mi] = *reinterpret_cast<const short8*>(
                    At + (wm + mi * 16 + lc) * 64 + ks * 32 + lr * 8);
            #pragma unroll
            for (int ni = 0; ni < 4; ++ni)
                bf[ni] = *reinterpret_cast<const short8*>(
                    Bt + (wn + ni * 16 + lc) * 64 + ks * 32 + lr * 8);
            #pragma unroll
            for (int mi = 0; mi < 4; ++mi)
                #pragma unroll
                for (int ni = 0; ni < 4; ++ni)
                    acc[mi][ni] = __builtin_amdgcn_mfma_f32_16x16x32_bf16(
                        af[mi], bf[ni], acc[mi][ni], 0, 0, 0);
        }
    }

    // 768 is a multiple of 128, so the q/k/v section is uniform per block.
    const int sec = n0 / CSZ;
    const int nb = n0 - sec * CSZ;
    #pragma unroll
    for (int ni = 0; ni < 4; ++ni) {
        int ncol = wn + ni * 16 + lc;       // 0..127 within block
        int nn = nb + ncol;                 // 0..767 within section
        float badd = bias[n0 + ncol];
        int h = nn >> 6, d = nn & 63;
        #pragma unroll
        for (int mi = 0; mi < 4; ++mi) {
            #pragma unroll
            for (int r = 0; r < 4; ++r) {
                int m = m0 + wm + mi * 16 + lr * 4 + r;
                int bb = m >> 10, t = m & 1023;
                int plane = bb * N_HEADS + h;
                float v = acc[mi][ni][r] + badd;
                if (sec == 0)
                    qo[((size_t)plane * TSZ + t) * HD + d] = f2bf(v * 0.125f);
                else if (sec == 1)
                    ko[((size_t)plane * TSZ + t) * HD + d] = f2bf(v);
                else
                    vto[((size_t)plane * HD + d) * TSZ + t] = f2bf(v);
            }
        }
    }
}

// ---------------- causal-ReLU attention ----------------
// 2 waves per block; wave 0 handles q-tile j, wave 1 handles q-tile 15-j
// (perfect balance: 17 K-tile steps per block). Per wave:
// S^T = mfma(K_frag, Q_frag) -> mask+ReLU -> packed bf16 via cvt_pk ->
// ds_write_b64 -> PV from LDS S-frags and global v^T frags.
__global__ __launch_bounds__(128, 2) void attn_kernel(
    const unsigned short* __restrict__ q,    // [96][1024][64] bf16 (pre-scaled)
    const unsigned short* __restrict__ k,    // [96][1024][64] bf16
    const unsigned short* __restrict__ vt,   // [96][64][1024] bf16
    float* __restrict__ out)                 // [8][1024][768] f32
{
    __shared__ unsigned short smem[2 * 64 * LDA];
    const int wid = threadIdx.x >> 6;
    const int lane = threadIdx.x & 63;
    const int lr = lane >> 4, lc = lane & 15;
    const int qw = wid == 0 ? blockIdx.x : 15 - blockIdx.x;   // 0..15
    const int bh = blockIdx.y;               // 0..95
    const int b = bh / N_HEADS, h = bh - b * N_HEADS;
    const size_t base = (size_t)bh * (TSZ * HD);
    const int qrow0 = qw * 64;
    unsigned short* sm = smem + wid * 64 * LDA;

    // Q fragments (MFMA B operand for the S^T trick)
    short8 aq[2][4];
    #pragma unroll
    for (int ks = 0; ks < 2; ++ks)
        #pragma unroll
        for (int qi = 0; qi < 4; ++qi)
            aq[ks][qi] = *reinterpret_cast<const short8*>(
                q + base + (size_t)(qrow0 + qi * 16 + lc) * HD + ks * 32 + lr * 8);

    f32x4 y[4][4] = {};

    for (int kt = 0; kt <= qw; ++kt) {
        const int kv0 = kt * 64;
        f32x4 st[4][4] = {};   // S^T fragments: rows kv, cols q
        #pragma unroll
        for (int ks = 0; ks < 2; ++ks) {
            short8 ak[4];
            #pragma unroll
            for (int ki = 0; ki < 4; ++ki)
                ak[ki] = *reinterpret_cast<const short8*>(
                    k + base + (size_t)(kv0 + ki * 16 + lc) * HD + ks * 32 + lr * 8);
            #pragma unroll
            for (int ki = 0; ki < 4; ++ki)
                #pragma unroll
                for (int qi = 0; qi < 4; ++qi)
                    st[ki][qi] = __builtin_amdgcn_mfma_f32_16x16x32_bf16(
                        ak[ki], aq[ks][qi], st[ki][qi], 0, 0, 0);
        }
        const bool diag = (kt == qw);
        #pragma unroll
        for (int ki = 0; ki < 4; ++ki) {
            #pragma unroll
            for (int qi = 0; qi < 4; ++qi) {
                float vv[4];
                #pragma unroll
                for (int r = 0; r < 4; ++r) {
                    float s = fmaxf(st[ki][qi][r], 0.0f);          // ReLU
                    if (diag && (ki * 16 + lr * 4 + r > qi * 16 + lc))
                        s = 0.0f;                                   // causal mask
                    vv[r] = s;
                }
                __hip_bfloat162 p0 = __float22bfloat162_rn(make_float2(vv[0], vv[1]));
                __hip_bfloat162 p1 = __float22bfloat162_rn(make_float2(vv[2], vv[3]));
                uint2 pk;
                pk.x = *reinterpret_cast<unsigned*>(&p0);
                pk.y = *reinterpret_cast<unsigned*>(&p1);
                // S[q][kv] layout: 4 consecutive kv per lane -> one b64 write
                *reinterpret_cast<uint2*>(
                    sm + (qi * 16 + lc) * LDA + ki * 16 + lr * 4) = pk;
            }
        }
        // PV: y[q][d] += S[q][kv] * V[kv][d]  (V via transposed vt[d][kv])
        #pragma unroll
        for (int ks = 0; ks < 2; ++ks) {
            short8 as[4], bv[4];
            #pragma unroll
            for (int qi = 0; qi < 4; ++qi)
                as[qi] = *reinterpret_cast<const short8*>(
                    sm + (qi * 16 + lc) * LDA + ks * 32 + lr * 8);
            #pragma unroll
            for (int di = 0; di < 4; ++di)
                bv[di] = *reinterpret_cast<const short8*>(
                    vt + (size_t)bh * (HD * TSZ) + (size_t)(di * 16 + lc) * TSZ
                       + kv0 + ks * 32 + lr * 8);
            #pragma unroll
            for (int qi = 0; qi < 4; ++qi)
                #pragma unroll
                for (int di = 0; di < 4; ++di)
                    y[qi][di] = __builtin_amdgcn_mfma_f32_16x16x32_bf16(
                        as[qi], bv[di], y[qi][di], 0, 0, 0);
        }
    }

    #pragma unroll
    for (int qi = 0; qi < 4; ++qi)
        #pragma unroll
        for (int di = 0; di < 4; ++di)
            #pragma unroll
            for (int r = 0; r < 4; ++r) {
                int t = qrow0 + qi * 16 + lr * 4 + r;
                int d = di * 16 + lc;
                out[((size_t)b * TSZ + t) * CSZ + h * HD + d] = y[qi][di][r];
            }
}

extern "C" void kernel_launch(void* const* d_in, const int* in_sizes, int n_in,
                              void* d_out, int out_size, void* d_ws, size_t ws_size,
                              hipStream_t stream) {
    const float* x    = (const float*)d_in[0];
    const float* W    = (const float*)d_in[1];
    const float* bias = (const float*)d_in[2];
    float* out = (float*)d_out;

    unsigned short* xb  = (unsigned short*)d_ws;                 // 8192*768
    unsigned short* wb  = xb + (size_t)MSZ * CSZ;                // 2304*768
    unsigned short* qo  = wb + (size_t)N3 * CSZ;                 // 96*1024*64
    unsigned short* ko  = qo + (size_t)MSZ * CSZ;
    unsigned short* vto = ko + (size_t)MSZ * CSZ;

    const int nx = MSZ * CSZ;   // 6291456
    const int nw = N3 * CSZ;    // 1769472
    cvt_f32_to_bf16<<<nx / 1024, 256, 0, stream>>>(x, xb, nx);
    cvt_f32_to_bf16<<<nw / 1024, 256, 0, stream>>>(W, wb, nw);
    qkv_gemm<<<dim3(N3 / 128, MSZ / 128), 256, 0, stream>>>(xb, wb, bias, qo, ko, vto);
    attn_kernel<<<dim3(8, BSZ * N_HEADS), 128, 0, stream>>>(qo, ko, vto, out);
}